// Round 1
// baseline (578.520 us; speedup 1.0000x reference)
//
#include <hip/hip_runtime.h>
#include <hip/hip_bf16.h>
#include <cstdint>
#include <cstddef>

// Problem constants
#define B_  2
#define S_  4096
#define D_  512
#define H_  8
#define HD_ 64
#define SCALE_ 0.125f

typedef short s16x8 __attribute__((ext_vector_type(8)));
typedef float f32x4 __attribute__((ext_vector_type(4)));

__device__ __forceinline__ unsigned short f2bf(float f) {
    unsigned u = __builtin_bit_cast(unsigned, f);
    u += 0x7fffu + ((u >> 16) & 1u);   // round-to-nearest-even (finite values only)
    return (unsigned short)(u >> 16);
}

// ---------------------------------------------------------------------------
// Kernel 1: cast + transpose the four weight matrices to bf16, wt[n][k]
// ---------------------------------------------------------------------------
__global__ __launch_bounds__(256)
void prep_weights(const float* __restrict__ wq, const float* __restrict__ wk,
                  const float* __restrict__ wv, const float* __restrict__ wo,
                  unsigned short* __restrict__ wt) {
    int e = blockIdx.x * 256 + threadIdx.x;      // 4 * 512 * 512 total
    int mat = e >> 18;
    int i = e & 262143;
    int n = i >> 9, k = i & 511;
    const float* w = (mat == 0) ? wq : (mat == 1) ? wk : (mat == 2) ? wv : wo;
    wt[(size_t)mat * 262144 + n * 512 + k] = f2bf(w[k * 512 + n]);
}

// ---------------------------------------------------------------------------
// Kernel 2: GEMM  out = X[8192,512] @ W[512,512] + bias
//   IN_F32:   1 = X fp32 (cast to bf16 while staging), 0 = X bf16 (ushort)
//   OUT_MODE: 0 = bf16 [t][c]; 1 = bf16 head-transposed [b][h][hd][s]; 2 = fp32 [t][c]
// Block: 256 threads (4 waves), 64x64 output tile, BK=64, mfma 16x16x32 bf16.
// ---------------------------------------------------------------------------
template<int IN_F32, int OUT_MODE>
__global__ __launch_bounds__(256)
void proj_gemm(const void* __restrict__ xin, const unsigned short* __restrict__ wt,
               const float* __restrict__ bias, void* __restrict__ out) {
    __shared__ unsigned short xs[64 * 72];   // padded stride 72 (bank-conflict fix)
    __shared__ unsigned short wsd[64 * 72];

    const int tid  = threadIdx.x;
    const int wave = tid >> 6, lane = tid & 63;
    const int l15 = lane & 15, l4 = lane >> 4;
    const int row0 = blockIdx.x * 64, col0 = blockIdx.y * 64;
    const int sr = tid >> 2, seg = tid & 3;   // staging: 4 threads/row, 16 elems each

    f32x4 acc[4] = {};

    for (int kt = 0; kt < 512; kt += 64) {
        // ---- stage X tile (64 x 64 bf16) ----
        if (IN_F32) {
            const float* x = (const float*)xin + (size_t)(row0 + sr) * 512 + kt + seg * 16;
            unsigned short tmp[16];
            #pragma unroll
            for (int j = 0; j < 16; j += 4) {
                float4 v = *(const float4*)(x + j);
                tmp[j] = f2bf(v.x); tmp[j+1] = f2bf(v.y); tmp[j+2] = f2bf(v.z); tmp[j+3] = f2bf(v.w);
            }
            *(s16x8*)&xs[sr * 72 + seg * 16]     = *(s16x8*)&tmp[0];
            *(s16x8*)&xs[sr * 72 + seg * 16 + 8] = *(s16x8*)&tmp[8];
        } else {
            const unsigned short* x = (const unsigned short*)xin + (size_t)(row0 + sr) * 512 + kt + seg * 16;
            *(s16x8*)&xs[sr * 72 + seg * 16]     = *(const s16x8*)(x);
            *(s16x8*)&xs[sr * 72 + seg * 16 + 8] = *(const s16x8*)(x + 8);
        }
        // ---- stage W^T tile (wt layout [n][k], rows n, contiguous in k) ----
        {
            const unsigned short* wp = wt + (size_t)(col0 + sr) * 512 + kt + seg * 16;
            *(s16x8*)&wsd[sr * 72 + seg * 16]     = *(const s16x8*)(wp);
            *(s16x8*)&wsd[sr * 72 + seg * 16 + 8] = *(const s16x8*)(wp + 8);
        }
        __syncthreads();

        #pragma unroll
        for (int ks = 0; ks < 2; ++ks) {
            s16x8 a = *(const s16x8*)&xs[(wave * 16 + l15) * 72 + ks * 32 + l4 * 8];
            #pragma unroll
            for (int ng = 0; ng < 4; ++ng) {
                s16x8 b = *(const s16x8*)&wsd[(ng * 16 + l15) * 72 + ks * 32 + l4 * 8];
                acc[ng] = __builtin_amdgcn_mfma_f32_16x16x32_bf16(a, b, acc[ng], 0, 0, 0);
            }
        }
        __syncthreads();
    }

    // ---- epilogue: D[row=(l>>4)*4+r][col=16*ng+(l&15)] ----
    #pragma unroll
    for (int ng = 0; ng < 4; ++ng) {
        int c = col0 + ng * 16 + l15;
        float bv = bias[c];
        #pragma unroll
        for (int r = 0; r < 4; ++r) {
            int t = row0 + wave * 16 + l4 * 4 + r;
            float v = acc[ng][r] + bv;
            if (OUT_MODE == 0) {
                ((unsigned short*)out)[(size_t)t * 512 + c] = f2bf(v);
            } else if (OUT_MODE == 1) {
                int bb = t >> 12, s = t & 4095;
                int h = c >> 6, hd = c & 63;
                ((unsigned short*)out)[((size_t)(bb * H_ + h) * HD_ + hd) * S_ + s] = f2bf(v);
            } else {
                ((float*)out)[(size_t)t * 512 + c] = v;
            }
        }
    }
}

// ---------------------------------------------------------------------------
// Kernel 3: fused attention per (b,h,q-tile of 64 rows).
// Pass 1: streaming online (m,l). Pass 2: recompute scores, write normalized
// weights (fp32, via LDS for coalesced stores), accumulate O = P @ V (MFMA).
// ---------------------------------------------------------------------------
__global__ __launch_bounds__(256)
void attn_kernel(const unsigned short* __restrict__ qb,
                 const unsigned short* __restrict__ kb,
                 const unsigned short* __restrict__ vt,
                 float* __restrict__ wout,          // weights tensor base [B,H,S,S]
                 unsigned short* __restrict__ ob) { // pre-projection output, bf16 [t][512]
    __shared__ unsigned short kt_s[64 * 72];
    __shared__ unsigned short vt_s[64 * 72];
    __shared__ float w_s[64 * 68];

    const int tid  = threadIdx.x;
    const int wave = tid >> 6, lane = tid & 63;
    const int l15 = lane & 15, l4 = lane >> 4;
    const int q0 = blockIdx.x * 64;
    const int bh = blockIdx.y;
    const int b = bh >> 3, h = bh & 7;
    const int sr = tid >> 2, seg = tid & 3;

    // Q fragments held in registers for whole block lifetime
    s16x8 aq[2];
    {
        const int t = b * S_ + q0 + wave * 16 + l15;
        const unsigned short* qp = qb + (size_t)t * 512 + h * 64;
        aq[0] = *(const s16x8*)(qp + 0 * 32 + l4 * 8);
        aq[1] = *(const s16x8*)(qp + 1 * 32 + l4 * 8);
    }

    float m[4] = {-1e30f, -1e30f, -1e30f, -1e30f};
    float l[4] = {0.f, 0.f, 0.f, 0.f};

    // ---------------- pass 1: online max & denom ----------------
    for (int kt = 0; kt < 64; ++kt) {
        const int key0 = kt * 64;
        {
            const unsigned short* kp = kb + (size_t)(b * S_ + key0 + sr) * 512 + h * 64 + seg * 16;
            *(s16x8*)&kt_s[sr * 72 + seg * 16]     = *(const s16x8*)(kp);
            *(s16x8*)&kt_s[sr * 72 + seg * 16 + 8] = *(const s16x8*)(kp + 8);
        }
        __syncthreads();

        f32x4 sc[4] = {};
        #pragma unroll
        for (int ks = 0; ks < 2; ++ks)
            #pragma unroll
            for (int cg = 0; cg < 4; ++cg) {
                s16x8 bfr = *(const s16x8*)&kt_s[(cg * 16 + l15) * 72 + ks * 32 + l4 * 8];
                sc[cg] = __builtin_amdgcn_mfma_f32_16x16x32_bf16(aq[ks], bfr, sc[cg], 0, 0, 0);
            }

        #pragma unroll
        for (int r = 0; r < 4; ++r) {
            float s0 = sc[0][r] * SCALE_, s1 = sc[1][r] * SCALE_;
            float s2 = sc[2][r] * SCALE_, s3 = sc[3][r] * SCALE_;
            float tmax = fmaxf(fmaxf(s0, s1), fmaxf(s2, s3));
            #pragma unroll
            for (int off = 1; off < 16; off <<= 1)
                tmax = fmaxf(tmax, __shfl_xor(tmax, off));
            float mn = fmaxf(m[r], tmax);
            float ps = __expf(s0 - mn) + __expf(s1 - mn) + __expf(s2 - mn) + __expf(s3 - mn);
            #pragma unroll
            for (int off = 1; off < 16; off <<= 1)
                ps += __shfl_xor(ps, off);
            l[r] = l[r] * __expf(m[r] - mn) + ps;
            m[r] = mn;
        }
        __syncthreads();
    }

    float rl[4];
    #pragma unroll
    for (int r = 0; r < 4; ++r) rl[r] = 1.0f / l[r];

    // ---------------- pass 2: weights out + O accumulation ----------------
    f32x4 ao[4] = {};
    float* wbase = wout + ((size_t)bh * S_ + q0) * S_;

    for (int kt = 0; kt < 64; ++kt) {
        const int key0 = kt * 64;
        {
            const unsigned short* kp = kb + (size_t)(b * S_ + key0 + sr) * 512 + h * 64 + seg * 16;
            *(s16x8*)&kt_s[sr * 72 + seg * 16]     = *(const s16x8*)(kp);
            *(s16x8*)&kt_s[sr * 72 + seg * 16 + 8] = *(const s16x8*)(kp + 8);
            const unsigned short* vp = vt + ((size_t)bh * HD_ + sr) * S_ + key0 + seg * 16;
            *(s16x8*)&vt_s[sr * 72 + seg * 16]     = *(const s16x8*)(vp);
            *(s16x8*)&vt_s[sr * 72 + seg * 16 + 8] = *(const s16x8*)(vp + 8);
        }
        __syncthreads();

        f32x4 sc[4] = {};
        #pragma unroll
        for (int ks = 0; ks < 2; ++ks)
            #pragma unroll
            for (int cg = 0; cg < 4; ++cg) {
                s16x8 bfr = *(const s16x8*)&kt_s[(cg * 16 + l15) * 72 + ks * 32 + l4 * 8];
                sc[cg] = __builtin_amdgcn_mfma_f32_16x16x32_bf16(aq[ks], bfr, sc[cg], 0, 0, 0);
            }

        // normalized weights -> LDS tile (row = strip row, col = key)
        #pragma unroll
        for (int cg = 0; cg < 4; ++cg)
            #pragma unroll
            for (int r = 0; r < 4; ++r) {
                float wv = __expf(sc[cg][r] * SCALE_ - m[r]) * rl[r];
                w_s[(wave * 16 + l4 * 4 + r) * 68 + cg * 16 + l15] = wv;
            }
        __syncthreads();

        // coalesced fp32 weights store: each wave writes its 16 rows, 256B each
        #pragma unroll
        for (int i = 0; i < 16; ++i) {
            int row = wave * 16 + i;
            wbase[(size_t)row * S_ + key0 + lane] = w_s[row * 68 + lane];
        }

        // PV: A = weights (cast to bf16 from LDS), B = V^T tile
        #pragma unroll
        for (int ks = 0; ks < 2; ++ks) {
            const float* wr = &w_s[(wave * 16 + l15) * 68 + ks * 32 + l4 * 8];
            float4 wa0 = *(const float4*)(wr);
            float4 wa1 = *(const float4*)(wr + 4);
            unsigned short tmp[8] = { f2bf(wa0.x), f2bf(wa0.y), f2bf(wa0.z), f2bf(wa0.w),
                                      f2bf(wa1.x), f2bf(wa1.y), f2bf(wa1.z), f2bf(wa1.w) };
            s16x8 a = *(s16x8*)tmp;
            #pragma unroll
            for (int ng = 0; ng < 4; ++ng) {
                s16x8 bfr = *(const s16x8*)&vt_s[(ng * 16 + l15) * 72 + ks * 32 + l4 * 8];
                ao[ng] = __builtin_amdgcn_mfma_f32_16x16x32_bf16(a, bfr, ao[ng], 0, 0, 0);
            }
        }
        __syncthreads();
    }

    // store O tile (pre-projection) as bf16 [t][512]
    #pragma unroll
    for (int ng = 0; ng < 4; ++ng) {
        int hd = ng * 16 + l15;
        #pragma unroll
        for (int r = 0; r < 4; ++r) {
            int t = b * S_ + q0 + wave * 16 + l4 * 4 + r;
            ob[(size_t)t * 512 + h * 64 + hd] = f2bf(ao[ng][r]);
        }
    }
}

// ---------------------------------------------------------------------------
// Launch
// ---------------------------------------------------------------------------
extern "C" void kernel_launch(void* const* d_in, const int* in_sizes, int n_in,
                              void* d_out, int out_size, void* d_ws, size_t ws_size,
                              hipStream_t stream) {
    (void)in_sizes; (void)n_in; (void)out_size; (void)ws_size;

    const float* query = (const float*)d_in[0];
    const float* key_  = (const float*)d_in[1];
    const float* value = (const float*)d_in[2];
    const float* wq = (const float*)d_in[3];
    const float* bq = (const float*)d_in[4];
    const float* wk = (const float*)d_in[5];
    const float* bk = (const float*)d_in[6];
    const float* wv = (const float*)d_in[7];
    const float* bv = (const float*)d_in[8];
    const float* wo = (const float*)d_in[9];
    const float* bo = (const float*)d_in[10];
    float* out = (float*)d_out;

    // workspace layout (bytes): wt[4x512x512 bf16]=2MB, then qb/kb/vt/ob 8MB each (bf16)
    char* ws = (char*)d_ws;
    unsigned short* wt = (unsigned short*)(ws);
    unsigned short* qb = (unsigned short*)(ws + 2097152);
    unsigned short* kb = (unsigned short*)(ws + 2097152 + 1 * 8388608);
    unsigned short* vt = (unsigned short*)(ws + 2097152 + 2 * 8388608);
    unsigned short* ob = (unsigned short*)(ws + 2097152 + 3 * 8388608);

    hipLaunchKernelGGL(prep_weights, dim3(4096), dim3(256), 0, stream, wq, wk, wv, wo, wt);

    dim3 gg(128, 8);  // 8192/64 x 512/64
    hipLaunchKernelGGL((proj_gemm<1, 0>), gg, dim3(256), 0, stream, query, wt,              bq, qb);
    hipLaunchKernelGGL((proj_gemm<1, 0>), gg, dim3(256), 0, stream, key_,  wt + 262144,     bk, kb);
    hipLaunchKernelGGL((proj_gemm<1, 1>), gg, dim3(256), 0, stream, value, wt + 2 * 262144, bv, vt);

    hipLaunchKernelGGL(attn_kernel, dim3(64, 16), dim3(256), 0, stream,
                       qb, kb, vt, out + 4194304, ob);

    hipLaunchKernelGGL((proj_gemm<0, 2>), gg, dim3(256), 0, stream, ob, wt + 3 * 262144, bo, out);
}

// Round 2
// 504.522 us; speedup vs baseline: 1.1467x; 1.1467x over previous
//
#include <hip/hip_runtime.h>
#include <hip/hip_bf16.h>
#include <cstdint>
#include <cstddef>

// Problem constants
#define B_  2
#define S_  4096
#define D_  512
#define H_  8
#define HD_ 64
#define QSCALE_ 0.18033688f   // 0.125 * log2(e): scores come out in exp2 domain

typedef short s16x8 __attribute__((ext_vector_type(8)));
typedef float f32x4 __attribute__((ext_vector_type(4)));

__device__ __forceinline__ unsigned short f2bf(float f) {
    unsigned u = __builtin_bit_cast(unsigned, f);
    u += 0x7fffu + ((u >> 16) & 1u);   // round-to-nearest-even (finite values only)
    return (unsigned short)(u >> 16);
}

__device__ __forceinline__ unsigned packbf2(float a, float b) {
    unsigned r;
    asm("v_cvt_pk_bf16_f32 %0, %1, %2" : "=v"(r) : "v"(a), "v"(b));
    return r;
}

// ---------------------------------------------------------------------------
// Kernel 1: cast + transpose the four weight matrices to bf16, wt[n][k]
// ---------------------------------------------------------------------------
__global__ __launch_bounds__(256)
void prep_weights(const float* __restrict__ wq, const float* __restrict__ wk,
                  const float* __restrict__ wv, const float* __restrict__ wo,
                  unsigned short* __restrict__ wt) {
    int e = blockIdx.x * 256 + threadIdx.x;      // 4 * 512 * 512 total
    int mat = e >> 18;
    int i = e & 262143;
    int n = i >> 9, k = i & 511;
    const float* w = (mat == 0) ? wq : (mat == 1) ? wk : (mat == 2) ? wv : wo;
    wt[(size_t)mat * 262144 + n * 512 + k] = f2bf(w[k * 512 + n]);
}

// ---------------------------------------------------------------------------
// Kernel 2: GEMM  out = (X[8192,512] @ W[512,512] + bias) * oscale
//   IN_F32:   1 = X fp32 (cast to bf16 while staging), 0 = X bf16 (ushort)
//   OUT_MODE: 0 = bf16 [t][c]; 1 = bf16 head-transposed [b][h][hd][s]; 2 = fp32 [t][c]
// ---------------------------------------------------------------------------
template<int IN_F32, int OUT_MODE>
__global__ __launch_bounds__(256)
void proj_gemm(const void* __restrict__ xin, const unsigned short* __restrict__ wt,
               const float* __restrict__ bias, void* __restrict__ out, float oscale) {
    __shared__ unsigned short xs[64 * 72];   // padded stride 72 (bank-conflict fix)
    __shared__ unsigned short wsd[64 * 72];

    const int tid  = threadIdx.x;
    const int wave = tid >> 6, lane = tid & 63;
    const int l15 = lane & 15, l4 = lane >> 4;
    const int row0 = blockIdx.x * 64, col0 = blockIdx.y * 64;
    const int sr = tid >> 2, seg = tid & 3;   // staging: 4 threads/row, 16 elems each

    f32x4 acc[4] = {};

    for (int kt = 0; kt < 512; kt += 64) {
        if (IN_F32) {
            const float* x = (const float*)xin + (size_t)(row0 + sr) * 512 + kt + seg * 16;
            unsigned short tmp[16];
            #pragma unroll
            for (int j = 0; j < 16; j += 4) {
                float4 v = *(const float4*)(x + j);
                tmp[j] = f2bf(v.x); tmp[j+1] = f2bf(v.y); tmp[j+2] = f2bf(v.z); tmp[j+3] = f2bf(v.w);
            }
            *(s16x8*)&xs[sr * 72 + seg * 16]     = *(s16x8*)&tmp[0];
            *(s16x8*)&xs[sr * 72 + seg * 16 + 8] = *(s16x8*)&tmp[8];
        } else {
            const unsigned short* x = (const unsigned short*)xin + (size_t)(row0 + sr) * 512 + kt + seg * 16;
            *(s16x8*)&xs[sr * 72 + seg * 16]     = *(const s16x8*)(x);
            *(s16x8*)&xs[sr * 72 + seg * 16 + 8] = *(const s16x8*)(x + 8);
        }
        {
            const unsigned short* wp = wt + (size_t)(col0 + sr) * 512 + kt + seg * 16;
            *(s16x8*)&wsd[sr * 72 + seg * 16]     = *(const s16x8*)(wp);
            *(s16x8*)&wsd[sr * 72 + seg * 16 + 8] = *(const s16x8*)(wp + 8);
        }
        __syncthreads();

        #pragma unroll
        for (int ks = 0; ks < 2; ++ks) {
            s16x8 a = *(const s16x8*)&xs[(wave * 16 + l15) * 72 + ks * 32 + l4 * 8];
            #pragma unroll
            for (int ng = 0; ng < 4; ++ng) {
                s16x8 b = *(const s16x8*)&wsd[(ng * 16 + l15) * 72 + ks * 32 + l4 * 8];
                acc[ng] = __builtin_amdgcn_mfma_f32_16x16x32_bf16(a, b, acc[ng], 0, 0, 0);
            }
        }
        __syncthreads();
    }

    #pragma unroll
    for (int ng = 0; ng < 4; ++ng) {
        int c = col0 + ng * 16 + l15;
        float bv = bias[c];
        #pragma unroll
        for (int r = 0; r < 4; ++r) {
            int t = row0 + wave * 16 + l4 * 4 + r;
            float v = (acc[ng][r] + bv) * oscale;
            if (OUT_MODE == 0) {
                ((unsigned short*)out)[(size_t)t * 512 + c] = f2bf(v);
            } else if (OUT_MODE == 1) {
                int bb = t >> 12, s = t & 4095;
                int h = c >> 6, hd = c & 63;
                ((unsigned short*)out)[((size_t)(bb * H_ + h) * HD_ + hd) * S_ + s] = f2bf(v);
            } else {
                ((float*)out)[(size_t)t * 512 + c] = v;
            }
        }
    }
}

// ---------------------------------------------------------------------------
// Kernel 3: fused attention per (b,h,q-tile of 64 rows).
// Swapped QK^T (scores transposed: lane owns 4 consecutive kcols of one qrow).
// Max-free exp2-domain softmax (safe: |pre-scaled score| << 127).
// Pass 1: per-lane l = sum exp2(sc); merge across 4 lanes at end; off=-log2(l).
// Pass 2: w = exp2(sc+off); direct f32x4 global stores; bf16 pack -> wave-
//         private LDS strip -> PV MFMA.
// ---------------------------------------------------------------------------
__global__ __launch_bounds__(256)
void attn_kernel(const unsigned short* __restrict__ qb,
                 const unsigned short* __restrict__ kb,
                 const unsigned short* __restrict__ vt,
                 float* __restrict__ wout,          // weights tensor base [B,H,S,S]
                 unsigned short* __restrict__ ob) { // pre-projection output, bf16 [t][512]
    __shared__ unsigned short kt_s[64 * 72];
    __shared__ unsigned short vt_s[64 * 72];
    __shared__ unsigned short w_s[64 * 68];   // bf16 P, per-wave-private 16-row strips

    const int tid  = threadIdx.x;
    const int wave = tid >> 6, lane = tid & 63;
    const int l15 = lane & 15, l4 = lane >> 4;

    // XCD-aware swizzle: all 64 q-tiles of one (b,h) on the same XCD
    const int lid = blockIdx.x;                  // 0..1023
    const int wid = (lid & 7) * 128 + (lid >> 3);
    const int bh = wid >> 6;
    const int q0 = (wid & 63) * 64;
    const int b = bh >> 3, h = bh & 7;
    const int sr = tid >> 2, seg = tid & 3;

    // Q fragments (pre-scaled by 0.125*log2e in the projection)
    s16x8 aq[2];
    {
        const int t = b * S_ + q0 + wave * 16 + l15;
        const unsigned short* qp = qb + (size_t)t * 512 + h * 64;
        aq[0] = *(const s16x8*)(qp + 0 * 32 + l4 * 8);
        aq[1] = *(const s16x8*)(qp + 1 * 32 + l4 * 8);
    }

    // ---------------- pass 1: per-lane denom, no max, no per-tile shuffles ---
    float lsum = 0.0f;
    for (int kt = 0; kt < 64; ++kt) {
        const int key0 = kt * 64;
        {
            const unsigned short* kp = kb + (size_t)(b * S_ + key0 + sr) * 512 + h * 64 + seg * 16;
            *(s16x8*)&kt_s[sr * 72 + seg * 16]     = *(const s16x8*)(kp);
            *(s16x8*)&kt_s[sr * 72 + seg * 16 + 8] = *(const s16x8*)(kp + 8);
        }
        __syncthreads();

        f32x4 sc[4] = {};
        #pragma unroll
        for (int ks = 0; ks < 2; ++ks)
            #pragma unroll
            for (int cg = 0; cg < 4; ++cg) {
                s16x8 afr = *(const s16x8*)&kt_s[(cg * 16 + l15) * 72 + ks * 32 + l4 * 8];
                sc[cg] = __builtin_amdgcn_mfma_f32_16x16x32_bf16(afr, aq[ks], sc[cg], 0, 0, 0);
            }

        #pragma unroll
        for (int cg = 0; cg < 4; ++cg)
            #pragma unroll
            for (int r = 0; r < 4; ++r)
                lsum += __builtin_amdgcn_exp2f(sc[cg][r]);
        __syncthreads();
    }

    lsum += __shfl_xor(lsum, 16);
    lsum += __shfl_xor(lsum, 32);
    const float off = -__builtin_amdgcn_logf(lsum);   // v_log_f32 = log2

    // ---------------- pass 2: weights out + O accumulation ----------------
    f32x4 ao[4] = {};
    float* wrow = wout + ((size_t)bh * S_ + q0 + wave * 16 + l15) * S_;

    for (int kt = 0; kt < 64; ++kt) {
        const int key0 = kt * 64;
        {
            const unsigned short* kp = kb + (size_t)(b * S_ + key0 + sr) * 512 + h * 64 + seg * 16;
            *(s16x8*)&kt_s[sr * 72 + seg * 16]     = *(const s16x8*)(kp);
            *(s16x8*)&kt_s[sr * 72 + seg * 16 + 8] = *(const s16x8*)(kp + 8);
            const unsigned short* vp = vt + ((size_t)bh * HD_ + sr) * S_ + key0 + seg * 16;
            *(s16x8*)&vt_s[sr * 72 + seg * 16]     = *(const s16x8*)(vp);
            *(s16x8*)&vt_s[sr * 72 + seg * 16 + 8] = *(const s16x8*)(vp + 8);
        }
        __syncthreads();

        f32x4 sc[4] = {};
        #pragma unroll
        for (int ks = 0; ks < 2; ++ks)
            #pragma unroll
            for (int cg = 0; cg < 4; ++cg) {
                s16x8 afr = *(const s16x8*)&kt_s[(cg * 16 + l15) * 72 + ks * 32 + l4 * 8];
                sc[cg] = __builtin_amdgcn_mfma_f32_16x16x32_bf16(afr, aq[ks], sc[cg], 0, 0, 0);
            }

        // normalized weights: w = exp2(sc + off); store f32x4 direct; pack bf16 to LDS
        #pragma unroll
        for (int cg = 0; cg < 4; ++cg) {
            f32x4 w;
            #pragma unroll
            for (int r = 0; r < 4; ++r)
                w[r] = __builtin_amdgcn_exp2f(sc[cg][r] + off);
            *(f32x4*)(wrow + key0 + cg * 16 + l4 * 4) = w;
            uint2 pk;
            pk.x = packbf2(w[0], w[1]);
            pk.y = packbf2(w[2], w[3]);
            *(uint2*)&w_s[(wave * 16 + l15) * 68 + cg * 16 + l4 * 4] = pk;
        }
        // wave-private strip: no barrier needed between write and read

        #pragma unroll
        for (int ks = 0; ks < 2; ++ks) {
            s16x8 pa = *(const s16x8*)&w_s[(wave * 16 + l15) * 68 + ks * 32 + l4 * 8];
            #pragma unroll
            for (int ng = 0; ng < 4; ++ng) {
                s16x8 bfr = *(const s16x8*)&vt_s[(ng * 16 + l15) * 72 + ks * 32 + l4 * 8];
                ao[ng] = __builtin_amdgcn_mfma_f32_16x16x32_bf16(pa, bfr, ao[ng], 0, 0, 0);
            }
        }
        __syncthreads();
    }

    // store O tile (pre-projection) as bf16 [t][512]
    #pragma unroll
    for (int ng = 0; ng < 4; ++ng) {
        int hd = ng * 16 + l15;
        #pragma unroll
        for (int r = 0; r < 4; ++r) {
            int t = b * S_ + q0 + wave * 16 + l4 * 4 + r;
            ob[(size_t)t * 512 + h * 64 + hd] = f2bf(ao[ng][r]);
        }
    }
}

// ---------------------------------------------------------------------------
// Launch
// ---------------------------------------------------------------------------
extern "C" void kernel_launch(void* const* d_in, const int* in_sizes, int n_in,
                              void* d_out, int out_size, void* d_ws, size_t ws_size,
                              hipStream_t stream) {
    (void)in_sizes; (void)n_in; (void)out_size; (void)ws_size;

    const float* query = (const float*)d_in[0];
    const float* key_  = (const float*)d_in[1];
    const float* value = (const float*)d_in[2];
    const float* wq = (const float*)d_in[3];
    const float* bq = (const float*)d_in[4];
    const float* wk = (const float*)d_in[5];
    const float* bk = (const float*)d_in[6];
    const float* wv = (const float*)d_in[7];
    const float* bv = (const float*)d_in[8];
    const float* wo = (const float*)d_in[9];
    const float* bo = (const float*)d_in[10];
    float* out = (float*)d_out;

    // workspace layout (bytes): wt[4x512x512 bf16]=2MB, then qb/kb/vt/ob 8MB each (bf16)
    char* ws = (char*)d_ws;
    unsigned short* wt = (unsigned short*)(ws);
    unsigned short* qb = (unsigned short*)(ws + 2097152);
    unsigned short* kb = (unsigned short*)(ws + 2097152 + 1 * 8388608);
    unsigned short* vt = (unsigned short*)(ws + 2097152 + 2 * 8388608);
    unsigned short* ob = (unsigned short*)(ws + 2097152 + 3 * 8388608);

    hipLaunchKernelGGL(prep_weights, dim3(4096), dim3(256), 0, stream, wq, wk, wv, wo, wt);

    dim3 gg(128, 8);  // 8192/64 x 512/64
    hipLaunchKernelGGL((proj_gemm<1, 0>), gg, dim3(256), 0, stream, query, wt,              bq, qb, QSCALE_);
    hipLaunchKernelGGL((proj_gemm<1, 0>), gg, dim3(256), 0, stream, key_,  wt + 262144,     bk, kb, 1.0f);
    hipLaunchKernelGGL((proj_gemm<1, 1>), gg, dim3(256), 0, stream, value, wt + 2 * 262144, bv, vt, 1.0f);

    hipLaunchKernelGGL(attn_kernel, dim3(1024), dim3(256), 0, stream,
                       qb, kb, vt, out + 4194304, ob);

    hipLaunchKernelGGL((proj_gemm<0, 2>), gg, dim3(256), 0, stream, ob, wt + 3 * 262144, bo, out, 1.0f);
}